// Round 1
// baseline (739.907 us; speedup 1.0000x reference)
//
#include <hip/hip_runtime.h>
#include <hip/hip_bf16.h>

// Swin block, MI355X. Layouts:
//  x: (768, 96, 96) f32 CHW.  tokens: row-major (tok, C) bf16.
//  windowed token order: w = wh*12+ww, n = i*8+j, shifted pixel = ((wh*8+i+4)%96, (ww*8+j+4)%96)

typedef __attribute__((ext_vector_type(8))) short bf16x8;
typedef __attribute__((ext_vector_type(4))) float f32x4;

__device__ __forceinline__ short f2bf(float f){
  unsigned u = __builtin_bit_cast(unsigned, f);
  unsigned r = (u + 0x7FFFu + ((u >> 16) & 1u)) >> 16;
  return (short)r;
}
__device__ __forceinline__ float bf2f(short s){
  unsigned u = ((unsigned)(unsigned short)s) << 16;
  return __builtin_bit_cast(float, u);
}
__device__ __forceinline__ float gelu_tanh(float v){
  const float c = 0.7978845608028654f;
  float u = c * (v + 0.044715f * v * v * v);
  float e = __expf(2.f * u);
  float th = 1.f - 2.f / (e + 1.f);
  return 0.5f * v * (1.f + th);
}
__device__ __forceinline__ void gl2lds16(const short* g, short* l){
  __builtin_amdgcn_global_load_lds(
      (const __attribute__((address_space(1))) int*)g,
      (__attribute__((address_space(3))) int*)l, 16, 0, 0);
}

// ---------------- weight f32 -> bf16 ----------------
__global__ void k_f2b(const float* __restrict__ in, short* __restrict__ out, int n){
  int i = blockIdx.x * 256 + threadIdx.x;
  if (i < n) out[i] = f2bf(in[i]);
}

// ---------------- LN stats: per-pixel sum/sumsq over channels ----------------
__global__ void k_ln_stats(const float* __restrict__ x, float* __restrict__ sums,
                           float* __restrict__ sumsq){
  const int p = blockIdx.x * 256 + threadIdx.x;   // 0..9215
  const int c0 = blockIdx.y * 64;
  float s = 0.f, s2 = 0.f;
  for (int c = c0; c < c0 + 64; ++c){
    float v = x[(long)c * 9216 + p];
    s += v; s2 += v * v;
  }
  atomicAdd(&sums[p], s);
  atomicAdd(&sumsq[p], s2);
}
__global__ void k_ln_fin(const float* __restrict__ sums, const float* __restrict__ sumsq,
                         float* __restrict__ mean, float* __restrict__ rstd){
  const int p = blockIdx.x * 256 + threadIdx.x;
  float m = sums[p] * (1.f / 768.f);
  float v = sumsq[p] * (1.f / 768.f) - m * m;
  mean[p] = m;
  rstd[p] = rsqrtf(v + 1e-5f);
}

// ---------------- LN1 + shift + window partition -> bf16 tokens ----------------
__global__ void k_ln1_win(const float* __restrict__ x, const float* __restrict__ mean,
                          const float* __restrict__ rstd, const float* __restrict__ g,
                          const float* __restrict__ b, short* __restrict__ tok){
  __shared__ float tile[64][65];
  const int w = blockIdx.x, ct = blockIdx.y * 64;
  const int wh = w / 12, ww = w - wh * 12;
  const int t = threadIdx.x;
  for (int e = t; e < 4096; e += 256){        // lanes over pixels
    const int cl = e >> 6, pix = e & 63;
    int pr = wh * 8 + (pix >> 3) + 4; if (pr >= 96) pr -= 96;
    int pc = ww * 8 + (pix & 7) + 4;  if (pc >= 96) pc -= 96;
    tile[pix][cl] = x[(long)(ct + cl) * 9216 + pr * 96 + pc];
  }
  __syncthreads();
  for (int e = t; e < 4096; e += 256){        // lanes over channels
    const int pix = e >> 6, cl = e & 63;
    int pr = wh * 8 + (pix >> 3) + 4; if (pr >= 96) pr -= 96;
    int pc = ww * 8 + (pix & 7) + 4;  if (pc >= 96) pc -= 96;
    const int p = pr * 96 + pc;
    float v = (tile[pix][cl] - mean[p]) * rstd[p] * g[ct + cl] + b[ct + cl];
    tok[(long)(w * 64 + pix) * 768 + ct + cl] = f2bf(v);
  }
}

// ---------------- windowed residual merge: x1 = x + scatter(ptok) ----------------
__global__ void k_merge_win(const float* __restrict__ x, const short* __restrict__ ptok,
                            float* __restrict__ x1){
  __shared__ float tile[64][65];
  const int w = blockIdx.x, ct = blockIdx.y * 64;
  const int wh = w / 12, ww = w - wh * 12;
  const int t = threadIdx.x;
  for (int e = t; e < 4096; e += 256){        // lanes over channels (coalesced bf16 read)
    const int pix = e >> 6, cl = e & 63;
    tile[pix][cl] = bf2f(ptok[(long)(w * 64 + pix) * 768 + ct + cl]);
  }
  __syncthreads();
  for (int e = t; e < 4096; e += 256){        // lanes over pixels
    const int cl = e >> 6, pix = e & 63;
    int pr = wh * 8 + (pix >> 3) + 4; if (pr >= 96) pr -= 96;
    int pc = ww * 8 + (pix & 7) + 4;  if (pc >= 96) pc -= 96;
    const long gi = (long)(ct + cl) * 9216 + pr * 96 + pc;
    x1[gi] = x[gi] + tile[pix][cl];
  }
}

// ---------------- LN2 (raster order) -> bf16 tokens ----------------
__global__ void k_ln2_raster(const float* __restrict__ x1, const float* __restrict__ mean,
                             const float* __restrict__ rstd, const float* __restrict__ g,
                             const float* __restrict__ b, short* __restrict__ tok){
  __shared__ float tile[96][65];
  const int hrow = blockIdx.x, ct = blockIdx.y * 64;
  const int t = threadIdx.x;
  for (int e = t; e < 6144; e += 256){
    const int cl = e / 96, p = e - cl * 96;
    tile[p][cl] = x1[(long)(ct + cl) * 9216 + hrow * 96 + p];
  }
  __syncthreads();
  for (int e = t; e < 6144; e += 256){
    const int p = e >> 6, cl = e & 63;
    const int gp = hrow * 96 + p;
    float v = (tile[p][cl] - mean[gp]) * rstd[gp] * g[ct + cl] + b[ct + cl];
    tok[(long)gp * 768 + ct + cl] = f2bf(v);
  }
}

// ---------------- final merge (raster): out = x1 + mtok ----------------
__global__ void k_merge_raster(const float* __restrict__ x1, const short* __restrict__ mtok,
                               float* __restrict__ out){
  __shared__ float tile[96][65];
  const int hrow = blockIdx.x, ct = blockIdx.y * 64;
  const int t = threadIdx.x;
  for (int e = t; e < 6144; e += 256){
    const int p = e >> 6, cl = e & 63;
    tile[p][cl] = bf2f(mtok[(long)(hrow * 96 + p) * 768 + ct + cl]);
  }
  __syncthreads();
  for (int e = t; e < 6144; e += 256){
    const int cl = e / 96, p = e - cl * 96;
    const long gi = (long)(ct + cl) * 9216 + hrow * 96 + p;
    out[gi] = x1[gi] + tile[p][cl];
  }
}

// ---------------- MFMA GEMM: C[m,n] = A[m,:] . W[n,:] + bias[n] (opt GELU) ----------------
// 128x128 tile, BK=32, 4 waves, double-buffered LDS, global_load_lds width 16.
__global__ __launch_bounds__(256) void k_gemm_bt(
    const short* __restrict__ A, const short* __restrict__ B,
    const float* __restrict__ bias, short* __restrict__ C,
    int N, int K, int do_gelu)
{
  __shared__ short Al[2][4096];
  __shared__ short Bl[2][4096];
  const int tid = threadIdx.x;
  const int wave = tid >> 6, lane = tid & 63;
  const int l15 = lane & 15, lg = lane >> 4;
  const int bn = blockIdx.x, bm = blockIdx.y;
  const long Abase = (long)bm * 128 * K;
  const long Bbase = (long)bn * 128 * K;
  const int srow = tid >> 2;           // staging row (tid*8/32)
  const int scol = (tid & 3) << 3;     // staging col
  const int wr = (wave >> 1) * 64, wc = (wave & 1) * 64;

  f32x4 acc[4][4] = {};

  auto stage = [&](int buf, int k0){
    const short* gA = A + Abase + (long)srow * K + k0 + scol;
    const short* gB = B + Bbase + (long)srow * K + k0 + scol;
    short* lA = &Al[buf][wave * 512];
    short* lB = &Bl[buf][wave * 512];
    gl2lds16(gA, lA);
    gl2lds16(gA + (long)64 * K, lA + 2048);
    gl2lds16(gB, lB);
    gl2lds16(gB + (long)64 * K, lB + 2048);
  };

  const int NKT = K >> 5;
  int buf = 0;
  stage(0, 0);
  for (int kt = 0; kt < NKT; ++kt){
    if (kt + 1 < NKT) stage(buf ^ 1, (kt + 1) << 5);
    __syncthreads();
    bf16x8 af[4], bfv[4];
    #pragma unroll
    for (int m = 0; m < 4; ++m)
      af[m] = *(const bf16x8*)&Al[buf][(wr + m * 16 + l15) * 32 + lg * 8];
    #pragma unroll
    for (int n2 = 0; n2 < 4; ++n2)
      bfv[n2] = *(const bf16x8*)&Bl[buf][(wc + n2 * 16 + l15) * 32 + lg * 8];
    #pragma unroll
    for (int m = 0; m < 4; ++m)
      #pragma unroll
      for (int n2 = 0; n2 < 4; ++n2)
        acc[m][n2] = __builtin_amdgcn_mfma_f32_16x16x32_bf16(af[m], bfv[n2], acc[m][n2], 0, 0, 0);
    __syncthreads();
    buf ^= 1;
  }

  const long row0 = (long)bm * 128 + wr + lg * 4;
  const int col0 = bn * 128 + wc + l15;
  #pragma unroll
  for (int m = 0; m < 4; ++m){
    #pragma unroll
    for (int n2 = 0; n2 < 4; ++n2){
      const int col = col0 + n2 * 16;
      const float bb = bias[col];
      #pragma unroll
      for (int r = 0; r < 4; ++r){
        float v = acc[m][n2][r] + bb;
        if (do_gelu) v = gelu_tanh(v);
        C[(row0 + m * 16 + r) * (long)N + col] = f2bf(v);
      }
    }
  }
}

// ---------------- attention: one wave per (window, head), fp32 ----------------
__global__ void k_attn(const short* __restrict__ qkv, const float* __restrict__ btab,
                       short* __restrict__ out)
{
  const int bid = blockIdx.x;
  const int w = bid / 24, h = bid - w * 24;
  const int wh = w / 12, ww = w - wh * 12;
  const int n = threadIdx.x;                 // query index 0..63
  __shared__ float4 Kl[64][9];
  __shared__ float4 Vl[64][9];
  const long rowb = (long)(w * 64 + n) * 2304;

  #pragma unroll
  for (int c = 0; c < 4; ++c){
    bf16x8 kv = *(const bf16x8*)(qkv + rowb + 768 + h * 32 + c * 8);
    bf16x8 vv = *(const bf16x8*)(qkv + rowb + 1536 + h * 32 + c * 8);
    Kl[n][c * 2]     = make_float4(bf2f(kv[0]), bf2f(kv[1]), bf2f(kv[2]), bf2f(kv[3]));
    Kl[n][c * 2 + 1] = make_float4(bf2f(kv[4]), bf2f(kv[5]), bf2f(kv[6]), bf2f(kv[7]));
    Vl[n][c * 2]     = make_float4(bf2f(vv[0]), bf2f(vv[1]), bf2f(vv[2]), bf2f(vv[3]));
    Vl[n][c * 2 + 1] = make_float4(bf2f(vv[4]), bf2f(vv[5]), bf2f(vv[6]), bf2f(vv[7]));
  }
  const float scale = 0.17677669529663687f;  // 1/sqrt(32)
  float4 qv[8];
  #pragma unroll
  for (int c = 0; c < 4; ++c){
    bf16x8 qq = *(const bf16x8*)(qkv + rowb + h * 32 + c * 8);
    qv[c * 2]     = make_float4(bf2f(qq[0]) * scale, bf2f(qq[1]) * scale, bf2f(qq[2]) * scale, bf2f(qq[3]) * scale);
    qv[c * 2 + 1] = make_float4(bf2f(qq[4]) * scale, bf2f(qq[5]) * scale, bf2f(qq[6]) * scale, bf2f(qq[7]) * scale);
  }
  __syncthreads();

  const int i1 = n >> 3, j1 = n & 7;
  const int labn = ((wh == 11) ? ((i1 >= 4) ? 2 : 1) : 0) * 3 + ((ww == 11) ? ((j1 >= 4) ? 2 : 1) : 0);

  float s[64];
  #pragma unroll
  for (int m = 0; m < 64; ++m){
    float acc = 0.f;
    #pragma unroll
    for (int j = 0; j < 8; ++j){
      float4 kk = Kl[m][j];
      acc += qv[j].x * kk.x; acc += qv[j].y * kk.y;
      acc += qv[j].z * kk.z; acc += qv[j].w * kk.w;
    }
    const int i2 = m >> 3, j2 = m & 7;
    acc += btab[((i1 - i2 + 7) * 15 + (j1 - j2 + 7)) * 24 + h];
    const int labm = ((wh == 11) ? ((i2 >= 4) ? 2 : 1) : 0) * 3 + ((ww == 11) ? ((j2 >= 4) ? 2 : 1) : 0);
    s[m] = (labm == labn) ? acc : (acc - 100.f);
  }
  float mx = s[0];
  #pragma unroll
  for (int m = 1; m < 64; ++m) mx = fmaxf(mx, s[m]);
  float sum = 0.f;
  #pragma unroll
  for (int m = 0; m < 64; ++m){ float e = __expf(s[m] - mx); s[m] = e; sum += e; }
  const float inv = 1.f / sum;

  float4 ov[8];
  #pragma unroll
  for (int j = 0; j < 8; ++j) ov[j] = make_float4(0.f, 0.f, 0.f, 0.f);
  #pragma unroll
  for (int m = 0; m < 64; ++m){
    const float p = s[m];
    #pragma unroll
    for (int j = 0; j < 8; ++j){
      float4 vv = Vl[m][j];
      ov[j].x += p * vv.x; ov[j].y += p * vv.y;
      ov[j].z += p * vv.z; ov[j].w += p * vv.w;
    }
  }
  short* op = out + (long)(w * 64 + n) * 768 + h * 32;
  #pragma unroll
  for (int c = 0; c < 4; ++c){
    float4 a = ov[c * 2], b2 = ov[c * 2 + 1];
    bf16x8 r;
    r[0] = f2bf(a.x * inv); r[1] = f2bf(a.y * inv); r[2] = f2bf(a.z * inv); r[3] = f2bf(a.w * inv);
    r[4] = f2bf(b2.x * inv); r[5] = f2bf(b2.y * inv); r[6] = f2bf(b2.z * inv); r[7] = f2bf(b2.w * inv);
    *(bf16x8*)(op + c * 8) = r;
  }
}

// ---------------- launch ----------------
extern "C" void kernel_launch(void* const* d_in, const int* in_sizes, int n_in,
                              void* d_out, int out_size, void* d_ws, size_t ws_size,
                              hipStream_t stream)
{
  const float* x      = (const float*)d_in[0];
  const float* n1w    = (const float*)d_in[1];
  const float* n1b    = (const float*)d_in[2];
  const float* qkv_w  = (const float*)d_in[3];
  const float* qkv_b  = (const float*)d_in[4];
  const float* proj_w = (const float*)d_in[5];
  const float* proj_b = (const float*)d_in[6];
  const float* btab   = (const float*)d_in[7];
  const float* n2w    = (const float*)d_in[8];
  const float* n2b    = (const float*)d_in[9];
  const float* fc1_w  = (const float*)d_in[10];
  const float* fc1_b  = (const float*)d_in[11];
  const float* fc2_w  = (const float*)d_in[12];
  const float* fc2_b  = (const float*)d_in[13];
  float* out = (float*)d_out;
  char* ws = (char*)d_ws;

  short* WQ   = (short*)(ws + 0);           // 2304x768 bf16
  short* WP   = (short*)(ws + 3538944);     // 768x768
  short* W1   = (short*)(ws + 4718592);     // 3072x768
  short* W2   = (short*)(ws + 9437184);     // 768x3072
  float* SUMS = (float*)(ws + 14155776);    // 9216
  float* SUMSQ= (float*)(ws + 14192640);    // 9216
  float* MEAN = (float*)(ws + 14229504);
  float* RSTD = (float*)(ws + 14266368);
  short* TOK  = (short*)(ws + 14303232);    // 9216x768 bf16 (tok1, then tok2)
  short* BIG  = (short*)(ws + 28459008);    // 9216x2304 (qkv), then 9216x3072 (hid)
  short* ATT  = (short*)(ws + 85082112);    // 9216x768 (attn heads), then mlp out
  short* PRJ  = (short*)(ws + 99237888);    // 9216x768 proj out
  float* X1   = (float*)(ws + 113393664);   // 768x9216 f32

  k_f2b<<<(2304 * 768 + 255) / 256, 256, 0, stream>>>(qkv_w, WQ, 2304 * 768);
  k_f2b<<<(768 * 768 + 255) / 256, 256, 0, stream>>>(proj_w, WP, 768 * 768);
  k_f2b<<<(3072 * 768 + 255) / 256, 256, 0, stream>>>(fc1_w, W1, 3072 * 768);
  k_f2b<<<(768 * 3072 + 255) / 256, 256, 0, stream>>>(fc2_w, W2, 768 * 3072);

  hipMemsetAsync(SUMS, 0, 2 * 9216 * 4, stream);
  k_ln_stats<<<dim3(36, 12), 256, 0, stream>>>(x, SUMS, SUMSQ);
  k_ln_fin<<<36, 256, 0, stream>>>(SUMS, SUMSQ, MEAN, RSTD);
  k_ln1_win<<<dim3(144, 12), 256, 0, stream>>>(x, MEAN, RSTD, n1w, n1b, TOK);

  k_gemm_bt<<<dim3(18, 72), 256, 0, stream>>>(TOK, WQ, qkv_b, BIG, 2304, 768, 0);
  k_attn<<<3456, 64, 0, stream>>>(BIG, btab, ATT);
  k_gemm_bt<<<dim3(6, 72), 256, 0, stream>>>(ATT, WP, proj_b, PRJ, 768, 768, 0);
  k_merge_win<<<dim3(144, 12), 256, 0, stream>>>(x, PRJ, X1);

  hipMemsetAsync(SUMS, 0, 2 * 9216 * 4, stream);
  k_ln_stats<<<dim3(36, 12), 256, 0, stream>>>(X1, SUMS, SUMSQ);
  k_ln_fin<<<36, 256, 0, stream>>>(SUMS, SUMSQ, MEAN, RSTD);
  k_ln2_raster<<<dim3(96, 12), 256, 0, stream>>>(X1, MEAN, RSTD, n2w, n2b, TOK);

  k_gemm_bt<<<dim3(24, 72), 256, 0, stream>>>(TOK, W1, fc1_b, BIG, 3072, 768, 1);
  k_gemm_bt<<<dim3(6, 72), 256, 0, stream>>>(BIG, W2, fc2_b, ATT, 768, 3072, 0);
  k_merge_raster<<<dim3(96, 12), 256, 0, stream>>>(X1, ATT, out);
}

// Round 2
// 515.914 us; speedup vs baseline: 1.4342x; 1.4342x over previous
//
#include <hip/hip_runtime.h>
#include <hip/hip_bf16.h>

// Swin block, MI355X. Layouts:
//  x: (768, 96, 96) f32 CHW.  tokens: row-major (tok, C) bf16.
//  windowed token order: w = wh*12+ww, n = i*8+j, shifted pixel = ((wh*8+i+4)%96, (ww*8+j+4)%96)

typedef __attribute__((ext_vector_type(8))) short bf16x8;
typedef __attribute__((ext_vector_type(4))) float f32x4;

__device__ __forceinline__ short f2bf(float f){
  unsigned u = __builtin_bit_cast(unsigned, f);
  unsigned r = (u + 0x7FFFu + ((u >> 16) & 1u)) >> 16;
  return (short)r;
}
__device__ __forceinline__ float bf2f(short s){
  unsigned u = ((unsigned)(unsigned short)s) << 16;
  return __builtin_bit_cast(float, u);
}
__device__ __forceinline__ float gelu_tanh(float v){
  const float c = 0.7978845608028654f;
  float u = c * (v + 0.044715f * v * v * v);
  float e = __expf(2.f * u);
  float th = 1.f - 2.f / (e + 1.f);
  return 0.5f * v * (1.f + th);
}
__device__ __forceinline__ void gl2lds16(const short* g, short* l){
  __builtin_amdgcn_global_load_lds(
      (const __attribute__((address_space(1))) int*)g,
      (__attribute__((address_space(3))) int*)l, 16, 0, 0);
}

// ---------------- weight f32 -> bf16 ----------------
__global__ void k_f2b(const float* __restrict__ in, short* __restrict__ out, int n){
  int i = blockIdx.x * 256 + threadIdx.x;
  if (i < n) out[i] = f2bf(in[i]);
}

// ---------------- precompute rel-pos bias per (h, m, n) ----------------
__global__ void k_bias_pre(const float* __restrict__ btab, float* __restrict__ biasp){
  int idx = blockIdx.x * 256 + threadIdx.x;   // h*4096 + m*64 + n
  int h = idx >> 12, mn = idx & 4095, m = mn >> 6, n = mn & 63;
  int i1 = m >> 3, j1 = m & 7, i2 = n >> 3, j2 = n & 7;
  biasp[idx] = btab[((i1 - i2 + 7) * 15 + (j1 - j2 + 7)) * 24 + h];
}

// ---------------- LN stats: per-pixel sum/sumsq over channels ----------------
__global__ void k_ln_stats(const float* __restrict__ x, float* __restrict__ sums,
                           float* __restrict__ sumsq){
  const int p = blockIdx.x * 256 + threadIdx.x;   // 0..9215
  const int c0 = blockIdx.y * 64;
  float s = 0.f, s2 = 0.f;
  for (int c = c0; c < c0 + 64; ++c){
    float v = x[(long)c * 9216 + p];
    s += v; s2 += v * v;
  }
  atomicAdd(&sums[p], s);
  atomicAdd(&sumsq[p], s2);
}
__global__ void k_ln_fin(const float* __restrict__ sums, const float* __restrict__ sumsq,
                         float* __restrict__ mean, float* __restrict__ rstd){
  const int p = blockIdx.x * 256 + threadIdx.x;
  float m = sums[p] * (1.f / 768.f);
  float v = sumsq[p] * (1.f / 768.f) - m * m;
  mean[p] = m;
  rstd[p] = rsqrtf(v + 1e-5f);
}

// ---------------- LN1 + shift + window partition -> bf16 tokens ----------------
__global__ void k_ln1_win(const float* __restrict__ x, const float* __restrict__ mean,
                          const float* __restrict__ rstd, const float* __restrict__ g,
                          const float* __restrict__ b, short* __restrict__ tok){
  __shared__ float tile[64][65];
  const int w = blockIdx.x, ct = blockIdx.y * 64;
  const int wh = w / 12, ww = w - wh * 12;
  const int t = threadIdx.x;
  for (int e = t; e < 4096; e += 256){        // lanes over pixels
    const int cl = e >> 6, pix = e & 63;
    int pr = wh * 8 + (pix >> 3) + 4; if (pr >= 96) pr -= 96;
    int pc = ww * 8 + (pix & 7) + 4;  if (pc >= 96) pc -= 96;
    tile[pix][cl] = x[(long)(ct + cl) * 9216 + pr * 96 + pc];
  }
  __syncthreads();
  for (int e = t; e < 4096; e += 256){        // lanes over channels
    const int pix = e >> 6, cl = e & 63;
    int pr = wh * 8 + (pix >> 3) + 4; if (pr >= 96) pr -= 96;
    int pc = ww * 8 + (pix & 7) + 4;  if (pc >= 96) pc -= 96;
    const int p = pr * 96 + pc;
    float v = (tile[pix][cl] - mean[p]) * rstd[p] * g[ct + cl] + b[ct + cl];
    tok[(long)(w * 64 + pix) * 768 + ct + cl] = f2bf(v);
  }
}

// ---------------- windowed residual merge: x1 = x + scatter(ptok) ----------------
__global__ void k_merge_win(const float* __restrict__ x, const short* __restrict__ ptok,
                            float* __restrict__ x1){
  __shared__ float tile[64][65];
  const int w = blockIdx.x, ct = blockIdx.y * 64;
  const int wh = w / 12, ww = w - wh * 12;
  const int t = threadIdx.x;
  for (int e = t; e < 4096; e += 256){        // lanes over channels (coalesced bf16 read)
    const int pix = e >> 6, cl = e & 63;
    tile[pix][cl] = bf2f(ptok[(long)(w * 64 + pix) * 768 + ct + cl]);
  }
  __syncthreads();
  for (int e = t; e < 4096; e += 256){        // lanes over pixels
    const int cl = e >> 6, pix = e & 63;
    int pr = wh * 8 + (pix >> 3) + 4; if (pr >= 96) pr -= 96;
    int pc = ww * 8 + (pix & 7) + 4;  if (pc >= 96) pc -= 96;
    const long gi = (long)(ct + cl) * 9216 + pr * 96 + pc;
    x1[gi] = x[gi] + tile[pix][cl];
  }
}

// ---------------- LN2 (raster order) -> bf16 tokens ----------------
__global__ void k_ln2_raster(const float* __restrict__ x1, const float* __restrict__ mean,
                             const float* __restrict__ rstd, const float* __restrict__ g,
                             const float* __restrict__ b, short* __restrict__ tok){
  __shared__ float tile[96][65];
  const int hrow = blockIdx.x, ct = blockIdx.y * 64;
  const int t = threadIdx.x;
  for (int e = t; e < 6144; e += 256){
    const int cl = e / 96, p = e - cl * 96;
    tile[p][cl] = x1[(long)(ct + cl) * 9216 + hrow * 96 + p];
  }
  __syncthreads();
  for (int e = t; e < 6144; e += 256){
    const int p = e >> 6, cl = e & 63;
    const int gp = hrow * 96 + p;
    float v = (tile[p][cl] - mean[gp]) * rstd[gp] * g[ct + cl] + b[ct + cl];
    tok[(long)gp * 768 + ct + cl] = f2bf(v);
  }
}

// ---------------- final merge (raster): out = x1 + mtok ----------------
__global__ void k_merge_raster(const float* __restrict__ x1, const short* __restrict__ mtok,
                               float* __restrict__ out){
  __shared__ float tile[96][65];
  const int hrow = blockIdx.x, ct = blockIdx.y * 64;
  const int t = threadIdx.x;
  for (int e = t; e < 6144; e += 256){
    const int p = e >> 6, cl = e & 63;
    tile[p][cl] = bf2f(mtok[(long)(hrow * 96 + p) * 768 + ct + cl]);
  }
  __syncthreads();
  for (int e = t; e < 6144; e += 256){
    const int cl = e / 96, p = e - cl * 96;
    const long gi = (long)(ct + cl) * 9216 + hrow * 96 + p;
    out[gi] = x1[gi] + tile[p][cl];
  }
}

// ---------------- MFMA GEMM: C[m,n] = A[m,:] . W[n,:] + bias[n] (opt GELU) ----------------
__global__ __launch_bounds__(256) void k_gemm_bt(
    const short* __restrict__ A, const short* __restrict__ B,
    const float* __restrict__ bias, short* __restrict__ C,
    int N, int K, int do_gelu)
{
  __shared__ short Al[2][4096];
  __shared__ short Bl[2][4096];
  const int tid = threadIdx.x;
  const int wave = tid >> 6, lane = tid & 63;
  const int l15 = lane & 15, lg = lane >> 4;
  const int bn = blockIdx.x, bm = blockIdx.y;
  const long Abase = (long)bm * 128 * K;
  const long Bbase = (long)bn * 128 * K;
  const int srow = tid >> 2;           // staging row (tid*8/32)
  const int scol = (tid & 3) << 3;     // staging col
  const int wr = (wave >> 1) * 64, wc = (wave & 1) * 64;

  f32x4 acc[4][4] = {};

  auto stage = [&](int buf, int k0){
    const short* gA = A + Abase + (long)srow * K + k0 + scol;
    const short* gB = B + Bbase + (long)srow * K + k0 + scol;
    short* lA = &Al[buf][wave * 512];
    short* lB = &Bl[buf][wave * 512];
    gl2lds16(gA, lA);
    gl2lds16(gA + (long)64 * K, lA + 2048);
    gl2lds16(gB, lB);
    gl2lds16(gB + (long)64 * K, lB + 2048);
  };

  const int NKT = K >> 5;
  int buf = 0;
  stage(0, 0);
  for (int kt = 0; kt < NKT; ++kt){
    if (kt + 1 < NKT) stage(buf ^ 1, (kt + 1) << 5);
    __syncthreads();
    bf16x8 af[4], bfv[4];
    #pragma unroll
    for (int m = 0; m < 4; ++m)
      af[m] = *(const bf16x8*)&Al[buf][(wr + m * 16 + l15) * 32 + lg * 8];
    #pragma unroll
    for (int n2 = 0; n2 < 4; ++n2)
      bfv[n2] = *(const bf16x8*)&Bl[buf][(wc + n2 * 16 + l15) * 32 + lg * 8];
    #pragma unroll
    for (int m = 0; m < 4; ++m)
      #pragma unroll
      for (int n2 = 0; n2 < 4; ++n2)
        acc[m][n2] = __builtin_amdgcn_mfma_f32_16x16x32_bf16(af[m], bfv[n2], acc[m][n2], 0, 0, 0);
    __syncthreads();
    buf ^= 1;
  }

  const long row0 = (long)bm * 128 + wr + lg * 4;
  const int col0 = bn * 128 + wc + l15;
  #pragma unroll
  for (int m = 0; m < 4; ++m){
    #pragma unroll
    for (int n2 = 0; n2 < 4; ++n2){
      const int col = col0 + n2 * 16;
      const float bb = bias[col];
      #pragma unroll
      for (int r = 0; r < 4; ++r){
        float v = acc[m][n2][r] + bb;
        if (do_gelu) v = gelu_tanh(v);
        C[(row0 + m * 16 + r) * (long)N + col] = f2bf(v);
      }
    }
  }
}

// ---------------- MFMA attention: one wave per (window, head) ----------------
// QK^T: 16 mfma_16x16x32 (dh=32 = one K-step). Softmax in C-fragment layout.
// P -> LDS bf16 (stride 72, 16B-aligned rows) -> A-frags. V^T frags from global.
#define PSTR 72
__global__ __launch_bounds__(256) void k_attn_mfma(
    const short* __restrict__ qkv, const float* __restrict__ biasp,
    short* __restrict__ out)
{
  __shared__ short Pl[4][64 * PSTR];
  const int tid = threadIdx.x, wv = tid >> 6, lane = tid & 63;
  const int l15 = lane & 15, lg = lane >> 4;
  const int task = blockIdx.x * 4 + wv;          // 0..3455
  const int w = task / 24, h = task - w * 24;
  const int wh = w / 12, ww = w - wh * 12;
  const long base = (long)w * 64 * 2304;
  const float scale = 0.17677669529663687f;      // 1/sqrt(32)

  // ---- QK^T ----
  bf16x8 qf[4], kf[4];
  #pragma unroll
  for (int mi = 0; mi < 4; ++mi)
    qf[mi] = *(const bf16x8*)(qkv + base + (long)(mi * 16 + l15) * 2304 + h * 32 + lg * 8);
  #pragma unroll
  for (int ni = 0; ni < 4; ++ni)
    kf[ni] = *(const bf16x8*)(qkv + base + (long)(ni * 16 + l15) * 2304 + 768 + h * 32 + lg * 8);

  f32x4 acc[4][4] = {};
  #pragma unroll
  for (int mi = 0; mi < 4; ++mi)
    #pragma unroll
    for (int ni = 0; ni < 4; ++ni)
      acc[mi][ni] = __builtin_amdgcn_mfma_f32_16x16x32_bf16(qf[mi], kf[ni], acc[mi][ni], 0, 0, 0);

  // ---- scale + bias + shift-mask (rows m = mi*16+lg*4+r, cols n = ni*16+l15) ----
  const float* bh = biasp + h * 4096;
  #pragma unroll
  for (int mi = 0; mi < 4; ++mi){
    #pragma unroll
    for (int r = 0; r < 4; ++r){
      const int m = mi * 16 + lg * 4 + r;
      const int i1 = m >> 3, j1 = m & 7;
      const int labm = ((wh == 11) ? ((i1 >= 4) ? 2 : 1) : 0) * 3
                     + ((ww == 11) ? ((j1 >= 4) ? 2 : 1) : 0);
      #pragma unroll
      for (int ni = 0; ni < 4; ++ni){
        const int n = ni * 16 + l15;
        const int i2 = n >> 3, j2 = n & 7;
        const int labn = ((wh == 11) ? ((i2 >= 4) ? 2 : 1) : 0) * 3
                       + ((ww == 11) ? ((j2 >= 4) ? 2 : 1) : 0);
        float s = acc[mi][ni][r] * scale + bh[m * 64 + n];
        if (labm != labn) s -= 100.f;
        acc[mi][ni][r] = s;
      }
    }
  }

  // ---- row softmax (reduce over ni in-lane, then 16-lane shfl_xor) ----
  float inv[4][4];
  #pragma unroll
  for (int mi = 0; mi < 4; ++mi){
    #pragma unroll
    for (int r = 0; r < 4; ++r){
      float mx = fmaxf(fmaxf(acc[mi][0][r], acc[mi][1][r]),
                       fmaxf(acc[mi][2][r], acc[mi][3][r]));
      #pragma unroll
      for (int off = 1; off < 16; off <<= 1) mx = fmaxf(mx, __shfl_xor(mx, off));
      float sum = 0.f;
      #pragma unroll
      for (int ni = 0; ni < 4; ++ni){
        float e = __expf(acc[mi][ni][r] - mx);
        acc[mi][ni][r] = e;
        sum += e;
      }
      #pragma unroll
      for (int off = 1; off < 16; off <<= 1) sum += __shfl_xor(sum, off);
      inv[mi][r] = 1.f / sum;
    }
  }

  // ---- P -> LDS bf16 ----
  short* pw = &Pl[wv][0];
  #pragma unroll
  for (int mi = 0; mi < 4; ++mi)
    #pragma unroll
    for (int ni = 0; ni < 4; ++ni)
      #pragma unroll
      for (int r = 0; r < 4; ++r)
        pw[(mi * 16 + lg * 4 + r) * PSTR + ni * 16 + l15] = f2bf(acc[mi][ni][r]);
  __syncthreads();

  // ---- PV: O[64][32] = P[64][64] x V[64][32] ----
  f32x4 acc2[4][2] = {};
  #pragma unroll
  for (int kk = 0; kk < 2; ++kk){
    bf16x8 pa[4], vb[2];
    #pragma unroll
    for (int mi = 0; mi < 4; ++mi)
      pa[mi] = *(const bf16x8*)&pw[(mi * 16 + l15) * PSTR + kk * 32 + lg * 8];
    #pragma unroll
    for (int dj = 0; dj < 2; ++dj){
      bf16x8 t;
      #pragma unroll
      for (int e = 0; e < 8; ++e)
        t[e] = qkv[base + (long)(kk * 32 + lg * 8 + e) * 2304 + 1536 + h * 32 + dj * 16 + l15];
      vb[dj] = t;
    }
    #pragma unroll
    for (int mi = 0; mi < 4; ++mi)
      #pragma unroll
      for (int dj = 0; dj < 2; ++dj)
        acc2[mi][dj] = __builtin_amdgcn_mfma_f32_16x16x32_bf16(pa[mi], vb[dj], acc2[mi][dj], 0, 0, 0);
  }

  // ---- epilogue: normalize + store ----
  #pragma unroll
  for (int mi = 0; mi < 4; ++mi){
    #pragma unroll
    for (int r = 0; r < 4; ++r){
      const int m = mi * 16 + lg * 4 + r;
      const long ob = (long)(w * 64 + m) * 768 + h * 32;
      #pragma unroll
      for (int dj = 0; dj < 2; ++dj)
        out[ob + dj * 16 + l15] = f2bf(acc2[mi][dj][r] * inv[mi][r]);
    }
  }
}

// ---------------- launch ----------------
extern "C" void kernel_launch(void* const* d_in, const int* in_sizes, int n_in,
                              void* d_out, int out_size, void* d_ws, size_t ws_size,
                              hipStream_t stream)
{
  const float* x      = (const float*)d_in[0];
  const float* n1w    = (const float*)d_in[1];
  const float* n1b    = (const float*)d_in[2];
  const float* qkv_w  = (const float*)d_in[3];
  const float* qkv_b  = (const float*)d_in[4];
  const float* proj_w = (const float*)d_in[5];
  const float* proj_b = (const float*)d_in[6];
  const float* btab   = (const float*)d_in[7];
  const float* n2w    = (const float*)d_in[8];
  const float* n2b    = (const float*)d_in[9];
  const float* fc1_w  = (const float*)d_in[10];
  const float* fc1_b  = (const float*)d_in[11];
  const float* fc2_w  = (const float*)d_in[12];
  const float* fc2_b  = (const float*)d_in[13];
  float* out = (float*)d_out;
  char* ws = (char*)d_ws;

  short* WQ   = (short*)(ws + 0);           // 2304x768 bf16
  short* WP   = (short*)(ws + 3538944);     // 768x768
  short* W1   = (short*)(ws + 4718592);     // 3072x768
  short* W2   = (short*)(ws + 9437184);     // 768x3072
  float* SUMS = (float*)(ws + 14155776);    // 9216
  float* SUMSQ= (float*)(ws + 14192640);    // 9216
  float* MEAN = (float*)(ws + 14229504);
  float* RSTD = (float*)(ws + 14266368);
  float* BIASP= (float*)(ws + 14303232);    // 24*64*64 f32 = 393216 B
  short* TOK  = (short*)(ws + 14696448);    // 9216x768 bf16
  short* BIG  = (short*)(ws + 28852224);    // 9216x2304 (qkv) / 9216x3072 (hid)
  short* ATT  = (short*)(ws + 85475328);    // 9216x768
  short* PRJ  = (short*)(ws + 99631104);    // 9216x768
  float* X1   = (float*)(ws + 113786880);   // 768x9216 f32

  k_f2b<<<(2304 * 768 + 255) / 256, 256, 0, stream>>>(qkv_w, WQ, 2304 * 768);
  k_f2b<<<(768 * 768 + 255) / 256, 256, 0, stream>>>(proj_w, WP, 768 * 768);
  k_f2b<<<(3072 * 768 + 255) / 256, 256, 0, stream>>>(fc1_w, W1, 3072 * 768);
  k_f2b<<<(768 * 3072 + 255) / 256, 256, 0, stream>>>(fc2_w, W2, 768 * 3072);
  k_bias_pre<<<(24 * 4096) / 256, 256, 0, stream>>>(btab, BIASP);

  hipMemsetAsync(SUMS, 0, 2 * 9216 * 4, stream);
  k_ln_stats<<<dim3(36, 12), 256, 0, stream>>>(x, SUMS, SUMSQ);
  k_ln_fin<<<36, 256, 0, stream>>>(SUMS, SUMSQ, MEAN, RSTD);
  k_ln1_win<<<dim3(144, 12), 256, 0, stream>>>(x, MEAN, RSTD, n1w, n1b, TOK);

  k_gemm_bt<<<dim3(18, 72), 256, 0, stream>>>(TOK, WQ, qkv_b, BIG, 2304, 768, 0);
  k_attn_mfma<<<864, 256, 0, stream>>>(BIG, BIASP, ATT);
  k_gemm_bt<<<dim3(6, 72), 256, 0, stream>>>(ATT, WP, proj_b, PRJ, 768, 768, 0);
  k_merge_win<<<dim3(144, 12), 256, 0, stream>>>(x, PRJ, X1);

  hipMemsetAsync(SUMS, 0, 2 * 9216 * 4, stream);
  k_ln_stats<<<dim3(36, 12), 256, 0, stream>>>(X1, SUMS, SUMSQ);
  k_ln_fin<<<36, 256, 0, stream>>>(SUMS, SUMSQ, MEAN, RSTD);
  k_ln2_raster<<<dim3(96, 12), 256, 0, stream>>>(X1, MEAN, RSTD, n2w, n2b, TOK);

  k_gemm_bt<<<dim3(24, 72), 256, 0, stream>>>(TOK, W1, fc1_b, BIG, 3072, 768, 1);
  k_gemm_bt<<<dim3(6, 72), 256, 0, stream>>>(BIG, W2, fc2_b, ATT, 768, 3072, 0);
  k_merge_raster<<<dim3(96, 12), 256, 0, stream>>>(X1, ATT, out);
}

// Round 3
// 507.128 us; speedup vs baseline: 1.4590x; 1.0173x over previous
//
#include <hip/hip_runtime.h>
#include <hip/hip_bf16.h>

// Swin block, MI355X. Layouts:
//  x: (768, 96, 96) f32 CHW.  tokens: row-major (tok, C) bf16.
//  windowed token order: w = wh*12+ww, n = i*8+j, shifted pixel = ((wh*8+i+4)%96, (ww*8+j+4)%96)

typedef __attribute__((ext_vector_type(8))) short bf16x8;
typedef __attribute__((ext_vector_type(4))) float f32x4;

__device__ __forceinline__ short f2bf(float f){
  unsigned u = __builtin_bit_cast(unsigned, f);
  unsigned r = (u + 0x7FFFu + ((u >> 16) & 1u)) >> 16;
  return (short)r;
}
__device__ __forceinline__ float bf2f(short s){
  unsigned u = ((unsigned)(unsigned short)s) << 16;
  return __builtin_bit_cast(float, u);
}
__device__ __forceinline__ float gelu_tanh(float v){
  const float c = 0.7978845608028654f;
  float u = c * (v + 0.044715f * v * v * v);
  float e = __expf(2.f * u);
  float th = 1.f - 2.f / (e + 1.f);
  return 0.5f * v * (1.f + th);
}
__device__ __forceinline__ void gl2lds16(const short* g, short* l){
  __builtin_amdgcn_global_load_lds(
      (const __attribute__((address_space(1))) int*)g,
      (__attribute__((address_space(3))) int*)l, 16, 0, 0);
}

// ---------------- weight f32 -> bf16 ----------------
__global__ void k_f2b(const float* __restrict__ in, short* __restrict__ out, int n){
  int i = blockIdx.x * 256 + threadIdx.x;
  if (i < n) out[i] = f2bf(in[i]);
}

// ---------------- precompute rel-pos bias per (h, m, n) ----------------
__global__ void k_bias_pre(const float* __restrict__ btab, float* __restrict__ biasp){
  int idx = blockIdx.x * 256 + threadIdx.x;   // h*4096 + m*64 + n
  int h = idx >> 12, mn = idx & 4095, m = mn >> 6, n = mn & 63;
  int i1 = m >> 3, j1 = m & 7, i2 = n >> 3, j2 = n & 7;
  biasp[idx] = btab[((i1 - i2 + 7) * 15 + (j1 - j2 + 7)) * 24 + h];
}

// ---------------- LN stats: per-pixel sum/sumsq over channels ----------------
__global__ void k_ln_stats(const float* __restrict__ x, float* __restrict__ sums,
                           float* __restrict__ sumsq){
  const int p = blockIdx.x * 256 + threadIdx.x;   // 0..9215
  const int c0 = blockIdx.y * 64;
  float s = 0.f, s2 = 0.f;
  for (int c = c0; c < c0 + 64; ++c){
    float v = x[(long)c * 9216 + p];
    s += v; s2 += v * v;
  }
  atomicAdd(&sums[p], s);
  atomicAdd(&sumsq[p], s2);
}
__global__ void k_ln_fin(const float* __restrict__ sums, const float* __restrict__ sumsq,
                         float* __restrict__ mean, float* __restrict__ rstd){
  const int p = blockIdx.x * 256 + threadIdx.x;
  float m = sums[p] * (1.f / 768.f);
  float v = sumsq[p] * (1.f / 768.f) - m * m;
  mean[p] = m;
  rstd[p] = rsqrtf(v + 1e-5f);
}

// ---------------- LN1 + shift + window partition -> bf16 tokens ----------------
__global__ void k_ln1_win(const float* __restrict__ x, const float* __restrict__ mean,
                          const float* __restrict__ rstd, const float* __restrict__ g,
                          const float* __restrict__ b, short* __restrict__ tok){
  __shared__ float tile[64][65];
  const int w = blockIdx.x, ct = blockIdx.y * 64;
  const int wh = w / 12, ww = w - wh * 12;
  const int t = threadIdx.x;
  for (int e = t; e < 4096; e += 256){        // lanes over pixels
    const int cl = e >> 6, pix = e & 63;
    int pr = wh * 8 + (pix >> 3) + 4; if (pr >= 96) pr -= 96;
    int pc = ww * 8 + (pix & 7) + 4;  if (pc >= 96) pc -= 96;
    tile[pix][cl] = x[(long)(ct + cl) * 9216 + pr * 96 + pc];
  }
  __syncthreads();
  for (int e = t; e < 4096; e += 256){        // lanes over channels
    const int pix = e >> 6, cl = e & 63;
    int pr = wh * 8 + (pix >> 3) + 4; if (pr >= 96) pr -= 96;
    int pc = ww * 8 + (pix & 7) + 4;  if (pc >= 96) pc -= 96;
    const int p = pr * 96 + pc;
    float v = (tile[pix][cl] - mean[p]) * rstd[p] * g[ct + cl] + b[ct + cl];
    tok[(long)(w * 64 + pix) * 768 + ct + cl] = f2bf(v);
  }
}

// ---------------- windowed residual merge: x1 = x + scatter(ptok) ----------------
__global__ void k_merge_win(const float* __restrict__ x, const short* __restrict__ ptok,
                            float* __restrict__ x1){
  __shared__ float tile[64][65];
  const int w = blockIdx.x, ct = blockIdx.y * 64;
  const int wh = w / 12, ww = w - wh * 12;
  const int t = threadIdx.x;
  for (int e = t; e < 4096; e += 256){        // lanes over channels (coalesced bf16 read)
    const int pix = e >> 6, cl = e & 63;
    tile[pix][cl] = bf2f(ptok[(long)(w * 64 + pix) * 768 + ct + cl]);
  }
  __syncthreads();
  for (int e = t; e < 4096; e += 256){        // lanes over pixels
    const int cl = e >> 6, pix = e & 63;
    int pr = wh * 8 + (pix >> 3) + 4; if (pr >= 96) pr -= 96;
    int pc = ww * 8 + (pix & 7) + 4;  if (pc >= 96) pc -= 96;
    const long gi = (long)(ct + cl) * 9216 + pr * 96 + pc;
    x1[gi] = x[gi] + tile[pix][cl];
  }
}

// ---------------- LN2 (raster order) -> bf16 tokens ----------------
__global__ void k_ln2_raster(const float* __restrict__ x1, const float* __restrict__ mean,
                             const float* __restrict__ rstd, const float* __restrict__ g,
                             const float* __restrict__ b, short* __restrict__ tok){
  __shared__ float tile[96][65];
  const int hrow = blockIdx.x, ct = blockIdx.y * 64;
  const int t = threadIdx.x;
  for (int e = t; e < 6144; e += 256){
    const int cl = e / 96, p = e - cl * 96;
    tile[p][cl] = x1[(long)(ct + cl) * 9216 + hrow * 96 + p];
  }
  __syncthreads();
  for (int e = t; e < 6144; e += 256){
    const int p = e >> 6, cl = e & 63;
    const int gp = hrow * 96 + p;
    float v = (tile[p][cl] - mean[gp]) * rstd[gp] * g[ct + cl] + b[ct + cl];
    tok[(long)gp * 768 + ct + cl] = f2bf(v);
  }
}

// ---------------- final merge (raster): out = x1 + mtok ----------------
__global__ void k_merge_raster(const float* __restrict__ x1, const short* __restrict__ mtok,
                               float* __restrict__ out){
  __shared__ float tile[96][65];
  const int hrow = blockIdx.x, ct = blockIdx.y * 64;
  const int t = threadIdx.x;
  for (int e = t; e < 6144; e += 256){
    const int p = e >> 6, cl = e & 63;
    tile[p][cl] = bf2f(mtok[(long)(hrow * 96 + p) * 768 + ct + cl]);
  }
  __syncthreads();
  for (int e = t; e < 6144; e += 256){
    const int cl = e / 96, p = e - cl * 96;
    const long gi = (long)(ct + cl) * 9216 + hrow * 96 + p;
    out[gi] = x1[gi] + tile[p][cl];
  }
}

// ---------------- MFMA GEMM 128x128 (m97 structure) — used for N=768 GEMMs ----------------
__global__ __launch_bounds__(256) void k_gemm_bt(
    const short* __restrict__ A, const short* __restrict__ B,
    const float* __restrict__ bias, short* __restrict__ C,
    int N, int K, int do_gelu)
{
  __shared__ short Al[2][4096];
  __shared__ short Bl[2][4096];
  const int tid = threadIdx.x;
  const int wave = tid >> 6, lane = tid & 63;
  const int l15 = lane & 15, lg = lane >> 4;
  const int bn = blockIdx.x, bm = blockIdx.y;
  const long Abase = (long)bm * 128 * K;
  const long Bbase = (long)bn * 128 * K;
  const int srow = tid >> 2;
  const int scol = (tid & 3) << 3;
  const int wr = (wave >> 1) * 64, wc = (wave & 1) * 64;

  f32x4 acc[4][4] = {};

  auto stage = [&](int buf, int k0){
    const short* gA = A + Abase + (long)srow * K + k0 + scol;
    const short* gB = B + Bbase + (long)srow * K + k0 + scol;
    short* lA = &Al[buf][wave * 512];
    short* lB = &Bl[buf][wave * 512];
    gl2lds16(gA, lA);
    gl2lds16(gA + (long)64 * K, lA + 2048);
    gl2lds16(gB, lB);
    gl2lds16(gB + (long)64 * K, lB + 2048);
  };

  const int NKT = K >> 5;
  int buf = 0;
  stage(0, 0);
  for (int kt = 0; kt < NKT; ++kt){
    if (kt + 1 < NKT) stage(buf ^ 1, (kt + 1) << 5);
    __syncthreads();
    bf16x8 af[4], bfv[4];
    #pragma unroll
    for (int m = 0; m < 4; ++m)
      af[m] = *(const bf16x8*)&Al[buf][(wr + m * 16 + l15) * 32 + lg * 8];
    #pragma unroll
    for (int n2 = 0; n2 < 4; ++n2)
      bfv[n2] = *(const bf16x8*)&Bl[buf][(wc + n2 * 16 + l15) * 32 + lg * 8];
    #pragma unroll
    for (int m = 0; m < 4; ++m)
      #pragma unroll
      for (int n2 = 0; n2 < 4; ++n2)
        acc[m][n2] = __builtin_amdgcn_mfma_f32_16x16x32_bf16(af[m], bfv[n2], acc[m][n2], 0, 0, 0);
    __syncthreads();
    buf ^= 1;
  }

  const long row0 = (long)bm * 128 + wr + lg * 4;
  const int col0 = bn * 128 + wc + l15;
  #pragma unroll
  for (int m = 0; m < 4; ++m){
    #pragma unroll
    for (int n2 = 0; n2 < 4; ++n2){
      const int col = col0 + n2 * 16;
      const float bb = bias[col];
      #pragma unroll
      for (int r = 0; r < 4; ++r){
        float v = acc[m][n2][r] + bb;
        if (do_gelu) v = gelu_tanh(v);
        C[(row0 + m * 16 + r) * (long)N + col] = f2bf(v);
      }
    }
  }
}

// ---------------- MFMA GEMM 256x256, BK=64, 8 waves, 4-phase counted-vmcnt ----------------
// LDS 128KB: [buf2][op2][256 rows][64 cols] bf16, 128B rows, XOR-swizzled via
// pre-swizzled global source (linear gl2lds dest) + swizzled ds_read.
// Wave (wm,wn): rows fr*32+wm*16 (fr=0..7, halves split at fr=4), cols wn*64+nf*16.
// Per-tile issue order [B0,B1,A0,A1]; steady waits vmcnt(2)@ph0, vmcnt(4)@ph2.
__global__ __launch_bounds__(512, 2) void k_gemm256(
    const short* __restrict__ A, const short* __restrict__ B,
    const float* __restrict__ bias, short* __restrict__ C,
    int N, int K, int do_gelu)
{
  __shared__ short sm[65536];   // 128 KiB
  const int tid = threadIdx.x;
  const int w = tid >> 6, l = tid & 63;
  const int l15 = l & 15, lg = l >> 4;
  const int wm = w >> 2, wn = w & 3;
  const int bn = blockIdx.x, bm = blockIdx.y;
  const int xorb = l15 & 7;

  const int srow = w * 8 + (l >> 3);            // staging row within half
  const int scol = ((l & 7) ^ (l >> 3)) << 3;   // pre-swizzled k-chunk (elements)
  const long arow0 = (long)bm * 256, brow0 = (long)bn * 256;

  f32x4 acc[8][4] = {};

  auto stageH = [&](int p, int o, int H, int k0){
    const short* gb = (o ? B + (brow0 + H * 128 + srow) * (long)K
                         : A + (arow0 + H * 128 + srow) * (long)K) + k0 + scol;
    short* lb = &sm[(p * 2 + o) * 16384 + H * 8192 + w * 512];
    gl2lds16(gb, lb);
    gl2lds16(gb + (long)64 * K, lb + 4096);
  };

  // prologue: tile 0, order B0 B1 A0 A1
  stageH(0, 1, 0, 0); stageH(0, 1, 1, 0); stageH(0, 0, 0, 0); stageH(0, 0, 1, 0);

  const int NT = K >> 6;
  for (int t = 0; t < NT; ++t){
    const int p = t & 1;
    const int k1 = (t + 1) << 6;
    const bool pre = (t + 1 < NT);
    const int ab = (p * 2) * 16384, bb = (p * 2 + 1) * 16384;
    bf16x8 bfr[8];

#define PHASE_MFMA(f0)                                                          \
    __builtin_amdgcn_s_setprio(1);                                              \
    _Pragma("unroll")                                                           \
    for (int fi = 0; fi < 2; ++fi)                                              \
      _Pragma("unroll")                                                         \
      for (int nf = 0; nf < 4; ++nf)                                            \
        _Pragma("unroll")                                                       \
        for (int ks = 0; ks < 2; ++ks)                                          \
          acc[(f0) + fi][nf] = __builtin_amdgcn_mfma_f32_16x16x32_bf16(         \
              afr[fi][ks], bfr[nf * 2 + ks], acc[(f0) + fi][nf], 0, 0, 0);      \
    __builtin_amdgcn_s_setprio(0);

#define PHASE_AREAD(f0)                                                         \
    bf16x8 afr[2][2];                                                           \
    _Pragma("unroll")                                                           \
    for (int fi = 0; fi < 2; ++fi){                                             \
      const int ra = (((f0) + fi) * 32 + wm * 16 + l15) * 64;                   \
      _Pragma("unroll")                                                         \
      for (int ks = 0; ks < 2; ++ks)                                            \
        afr[fi][ks] = *(const bf16x8*)&sm[ab + ra + (((ks * 4 + lg) ^ xorb) << 3)]; \
    }

    // ---- phase 0: needs B0,B1,A0 of tile t ----
    asm volatile("s_waitcnt vmcnt(2)" ::: "memory");
    __builtin_amdgcn_s_barrier();
    {
      #pragma unroll
      for (int nf = 0; nf < 4; ++nf){
        const int rb = (wn * 64 + nf * 16 + l15) * 64;
        #pragma unroll
        for (int ks = 0; ks < 2; ++ks)
          bfr[nf * 2 + ks] = *(const bf16x8*)&sm[bb + rb + (((ks * 4 + lg) ^ xorb) << 3)];
      }
      PHASE_AREAD(0)
      if (pre) stageH(p ^ 1, 1, 0, k1);
      PHASE_MFMA(0)
    }
    // ---- phase 1 ----
    __builtin_amdgcn_s_barrier();
    {
      PHASE_AREAD(2)
      if (pre) stageH(p ^ 1, 1, 1, k1);
      PHASE_MFMA(2)
    }
    // ---- phase 2: needs A1 of tile t ----
    if (pre) asm volatile("s_waitcnt vmcnt(4)" ::: "memory");
    else     asm volatile("s_waitcnt vmcnt(0)" ::: "memory");
    __builtin_amdgcn_s_barrier();
    {
      PHASE_AREAD(4)
      if (pre) stageH(p ^ 1, 0, 0, k1);
      PHASE_MFMA(4)
    }
    // ---- phase 3 ----
    __builtin_amdgcn_s_barrier();
    {
      PHASE_AREAD(6)
      if (pre) stageH(p ^ 1, 0, 1, k1);
      PHASE_MFMA(6)
    }
#undef PHASE_MFMA
#undef PHASE_AREAD
  }

  // epilogue
  #pragma unroll
  for (int fr = 0; fr < 8; ++fr){
    const long row0 = (long)bm * 256 + fr * 32 + wm * 16 + lg * 4;
    #pragma unroll
    for (int nf = 0; nf < 4; ++nf){
      const int col = bn * 256 + wn * 64 + nf * 16 + l15;
      const float bb2 = bias[col];
      #pragma unroll
      for (int r = 0; r < 4; ++r){
        float v = acc[fr][nf][r] + bb2;
        if (do_gelu) v = gelu_tanh(v);
        C[(row0 + r) * (long)N + col] = f2bf(v);
      }
    }
  }
}

// ---------------- MFMA attention: one wave per (window, head) ----------------
#define PSTR 72
__global__ __launch_bounds__(256) void k_attn_mfma(
    const short* __restrict__ qkv, const float* __restrict__ biasp,
    short* __restrict__ out)
{
  __shared__ short Pl[4][64 * PSTR];
  const int tid = threadIdx.x, wv = tid >> 6, lane = tid & 63;
  const int l15 = lane & 15, lg = lane >> 4;
  const int task = blockIdx.x * 4 + wv;          // 0..3455
  const int w = task / 24, h = task - w * 24;
  const int wh = w / 12, ww = w - wh * 12;
  const long base = (long)w * 64 * 2304;
  const float scale = 0.17677669529663687f;      // 1/sqrt(32)

  bf16x8 qf[4], kf[4];
  #pragma unroll
  for (int mi = 0; mi < 4; ++mi)
    qf[mi] = *(const bf16x8*)(qkv + base + (long)(mi * 16 + l15) * 2304 + h * 32 + lg * 8);
  #pragma unroll
  for (int ni = 0; ni < 4; ++ni)
    kf[ni] = *(const bf16x8*)(qkv + base + (long)(ni * 16 + l15) * 2304 + 768 + h * 32 + lg * 8);

  f32x4 acc[4][4] = {};
  #pragma unroll
  for (int mi = 0; mi < 4; ++mi)
    #pragma unroll
    for (int ni = 0; ni < 4; ++ni)
      acc[mi][ni] = __builtin_amdgcn_mfma_f32_16x16x32_bf16(qf[mi], kf[ni], acc[mi][ni], 0, 0, 0);

  const float* bh = biasp + h * 4096;
  #pragma unroll
  for (int mi = 0; mi < 4; ++mi){
    #pragma unroll
    for (int r = 0; r < 4; ++r){
      const int m = mi * 16 + lg * 4 + r;
      const int i1 = m >> 3, j1 = m & 7;
      const int labm = ((wh == 11) ? ((i1 >= 4) ? 2 : 1) : 0) * 3
                     + ((ww == 11) ? ((j1 >= 4) ? 2 : 1) : 0);
      #pragma unroll
      for (int ni = 0; ni < 4; ++ni){
        const int n = ni * 16 + l15;
        const int i2 = n >> 3, j2 = n & 7;
        const int labn = ((wh == 11) ? ((i2 >= 4) ? 2 : 1) : 0) * 3
                       + ((ww == 11) ? ((j2 >= 4) ? 2 : 1) : 0);
        float s = acc[mi][ni][r] * scale + bh[m * 64 + n];
        if (labm != labn) s -= 100.f;
        acc[mi][ni][r] = s;
      }
    }
  }

  float inv[4][4];
  #pragma unroll
  for (int mi = 0; mi < 4; ++mi){
    #pragma unroll
    for (int r = 0; r < 4; ++r){
      float mx = fmaxf(fmaxf(acc[mi][0][r], acc[mi][1][r]),
                       fmaxf(acc[mi][2][r], acc[mi][3][r]));
      #pragma unroll
      for (int off = 1; off < 16; off <<= 1) mx = fmaxf(mx, __shfl_xor(mx, off));
      float sum = 0.f;
      #pragma unroll
      for (int ni = 0; ni < 4; ++ni){
        float e = __expf(acc[mi][ni][r] - mx);
        acc[mi][ni][r] = e;
        sum += e;
      }
      #pragma unroll
      for (int off = 1; off < 16; off <<= 1) sum += __shfl_xor(sum, off);
      inv[mi][r] = 1.f / sum;
    }
  }

  short* pw = &Pl[wv][0];
  #pragma unroll
  for (int mi = 0; mi < 4; ++mi)
    #pragma unroll
    for (int ni = 0; ni < 4; ++ni)
      #pragma unroll
      for (int r = 0; r < 4; ++r)
        pw[(mi * 16 + lg * 4 + r) * PSTR + ni * 16 + l15] = f2bf(acc[mi][ni][r]);
  __syncthreads();

  f32x4 acc2[4][2] = {};
  #pragma unroll
  for (int kk = 0; kk < 2; ++kk){
    bf16x8 pa[4], vb[2];
    #pragma unroll
    for (int mi = 0; mi < 4; ++mi)
      pa[mi] = *(const bf16x8*)&pw[(mi * 16 + l15) * PSTR + kk * 32 + lg * 8];
    #pragma unroll
    for (int dj = 0; dj < 2; ++dj){
      bf16x8 t;
      #pragma unroll
      for (int e = 0; e < 8; ++e)
        t[e] = qkv[base + (long)(kk * 32 + lg * 8 + e) * 2304 + 1536 + h * 32 + dj * 16 + l15];
      vb[dj] = t;
    }
    #pragma unroll
    for (int mi = 0; mi < 4; ++mi)
      #pragma unroll
      for (int dj = 0; dj < 2; ++dj)
        acc2[mi][dj] = __builtin_amdgcn_mfma_f32_16x16x32_bf16(pa[mi], vb[dj], acc2[mi][dj], 0, 0, 0);
  }

  #pragma unroll
  for (int mi = 0; mi < 4; ++mi){
    #pragma unroll
    for (int r = 0; r < 4; ++r){
      const int m = mi * 16 + lg * 4 + r;
      const long ob = (long)(w * 64 + m) * 768 + h * 32;
      #pragma unroll
      for (int dj = 0; dj < 2; ++dj)
        out[ob + dj * 16 + l15] = f2bf(acc2[mi][dj][r] * inv[mi][r]);
    }
  }
}

// ---------------- launch ----------------
extern "C" void kernel_launch(void* const* d_in, const int* in_sizes, int n_in,
                              void* d_out, int out_size, void* d_ws, size_t ws_size,
                              hipStream_t stream)
{
  const float* x      = (const float*)d_in[0];
  const float* n1w    = (const float*)d_in[1];
  const float* n1b    = (const float*)d_in[2];
  const float* qkv_w  = (const float*)d_in[3];
  const float* qkv_b  = (const float*)d_in[4];
  const float* proj_w = (const float*)d_in[5];
  const float* proj_b = (const float*)d_in[6];
  const float* btab   = (const float*)d_in[7];
  const float* n2w    = (const float*)d_in[8];
  const float* n2b    = (const float*)d_in[9];
  const float* fc1_w  = (const float*)d_in[10];
  const float* fc1_b  = (const float*)d_in[11];
  const float* fc2_w  = (const float*)d_in[12];
  const float* fc2_b  = (const float*)d_in[13];
  float* out = (float*)d_out;
  char* ws = (char*)d_ws;

  short* WQ   = (short*)(ws + 0);           // 2304x768 bf16
  short* WP   = (short*)(ws + 3538944);     // 768x768
  short* W1   = (short*)(ws + 4718592);     // 3072x768
  short* W2   = (short*)(ws + 9437184);     // 768x3072
  float* SUMS = (float*)(ws + 14155776);    // 9216
  float* SUMSQ= (float*)(ws + 14192640);    // 9216
  float* MEAN = (float*)(ws + 14229504);
  float* RSTD = (float*)(ws + 14266368);
  float* BIASP= (float*)(ws + 14303232);    // 24*64*64 f32
  short* TOK  = (short*)(ws + 14696448);    // 9216x768 bf16
  short* BIG  = (short*)(ws + 28852224);    // 9216x2304 (qkv) / 9216x3072 (hid)
  short* ATT  = (short*)(ws + 85475328);    // 9216x768
  short* PRJ  = (short*)(ws + 99631104);    // 9216x768
  float* X1   = (float*)(ws + 113786880);   // 768x9216 f32

  k_f2b<<<(2304 * 768 + 255) / 256, 256, 0, stream>>>(qkv_w, WQ, 2304 * 768);
  k_f2b<<<(768 * 768 + 255) / 256, 256, 0, stream>>>(proj_w, WP, 768 * 768);
  k_f2b<<<(3072 * 768 + 255) / 256, 256, 0, stream>>>(fc1_w, W1, 3072 * 768);
  k_f2b<<<(768 * 3072 + 255) / 256, 256, 0, stream>>>(fc2_w, W2, 768 * 3072);
  k_bias_pre<<<(24 * 4096) / 256, 256, 0, stream>>>(btab, BIASP);

  hipMemsetAsync(SUMS, 0, 2 * 9216 * 4, stream);
  k_ln_stats<<<dim3(36, 12), 256, 0, stream>>>(x, SUMS, SUMSQ);
  k_ln_fin<<<36, 256, 0, stream>>>(SUMS, SUMSQ, MEAN, RSTD);
  k_ln1_win<<<dim3(144, 12), 256, 0, stream>>>(x, MEAN, RSTD, n1w, n1b, TOK);

  k_gemm256<<<dim3(9, 36), 512, 0, stream>>>(TOK, WQ, qkv_b, BIG, 2304, 768, 0);
  k_attn_mfma<<<864, 256, 0, stream>>>(BIG, BIASP, ATT);
  k_gemm_bt<<<dim3(6, 72), 256, 0, stream>>>(ATT, WP, proj_b, PRJ, 768, 768, 0);
  k_merge_win<<<dim3(144, 12), 256, 0, stream>>>(x, PRJ, X1);

  hipMemsetAsync(SUMS, 0, 2 * 9216 * 4, stream);
  k_ln_stats<<<dim3(36, 12), 256, 0, stream>>>(X1, SUMS, SUMSQ);
  k_ln_fin<<<36, 256, 0, stream>>>(SUMS, SUMSQ, MEAN, RSTD);
  k_ln2_raster<<<dim3(96, 12), 256, 0, stream>>>(X1, MEAN, RSTD, n2w, n2b, TOK);

  k_gemm256<<<dim3(12, 36), 512, 0, stream>>>(TOK, W1, fc1_b, BIG, 3072, 768, 1);
  k_gemm_bt<<<dim3(6, 72), 256, 0, stream>>>(BIG, W2, fc2_b, ATT, 768, 3072, 0);
  k_merge_raster<<<dim3(96, 12), 256, 0, stream>>>(X1, ATT, out);
}

// Round 5
// 502.261 us; speedup vs baseline: 1.4732x; 1.0097x over previous
//
#include <hip/hip_runtime.h>
#include <hip/hip_bf16.h>

// Swin block, MI355X. Layouts:
//  x: (768, 96, 96) f32 CHW.  tokens: row-major (tok, C) bf16.
//  windowed token order: w = wh*12+ww, n = i*8+j, shifted pixel = ((wh*8+i+4)%96, (ww*8+j+4)%96)

typedef __attribute__((ext_vector_type(8))) short bf16x8;
typedef __attribute__((ext_vector_type(4))) float f32x4;

__device__ __forceinline__ short f2bf(float f){
  unsigned u = __builtin_bit_cast(unsigned, f);
  unsigned r = (u + 0x7FFFu + ((u >> 16) & 1u)) >> 16;
  return (short)r;
}
__device__ __forceinline__ float bf2f(short s){
  unsigned u = ((unsigned)(unsigned short)s) << 16;
  return __builtin_bit_cast(float, u);
}
__device__ __forceinline__ float gelu_tanh(float v){
  const float c = 0.7978845608028654f;
  float u = c * (v + 0.044715f * v * v * v);
  float e = __expf(2.f * u);
  float th = 1.f - 2.f / (e + 1.f);
  return 0.5f * v * (1.f + th);
}
__device__ __forceinline__ void gl2lds16(const short* g, short* l){
  __builtin_amdgcn_global_load_lds(
      (const __attribute__((address_space(1))) int*)g,
      (__attribute__((address_space(3))) int*)l, 16, 0, 0);
}

// ---------------- weight f32 -> bf16 ----------------
__global__ void k_f2b(const float* __restrict__ in, short* __restrict__ out, int n){
  int i = blockIdx.x * 256 + threadIdx.x;
  if (i < n) out[i] = f2bf(in[i]);
}

// ---------------- precompute rel-pos bias per (h, m, n) ----------------
__global__ void k_bias_pre(const float* __restrict__ btab, float* __restrict__ biasp){
  int idx = blockIdx.x * 256 + threadIdx.x;   // h*4096 + m*64 + n
  int h = idx >> 12, mn = idx & 4095, m = mn >> 6, n = mn & 63;
  int i1 = m >> 3, j1 = m & 7, i2 = n >> 3, j2 = n & 7;
  biasp[idx] = btab[((i1 - i2 + 7) * 15 + (j1 - j2 + 7)) * 24 + h];
}

// ---------------- LN stats: per-pixel sum/sumsq over channels ----------------
__global__ void k_ln_stats(const float* __restrict__ x, float* __restrict__ sums,
                           float* __restrict__ sumsq){
  const int p = blockIdx.x * 256 + threadIdx.x;   // 0..9215
  const int c0 = blockIdx.y * 64;
  float s = 0.f, s2 = 0.f;
  for (int c = c0; c < c0 + 64; ++c){
    float v = x[(long)c * 9216 + p];
    s += v; s2 += v * v;
  }
  atomicAdd(&sums[p], s);
  atomicAdd(&sumsq[p], s2);
}
__global__ void k_ln_fin(const float* __restrict__ sums, const float* __restrict__ sumsq,
                         float* __restrict__ mean, float* __restrict__ rstd){
  const int p = blockIdx.x * 256 + threadIdx.x;
  float m = sums[p] * (1.f / 768.f);
  float v = sumsq[p] * (1.f / 768.f) - m * m;
  mean[p] = m;
  rstd[p] = rsqrtf(v + 1e-5f);
}

// ---------------- LN1 + shift + window partition -> bf16 tokens ----------------
__global__ void k_ln1_win(const float* __restrict__ x, const float* __restrict__ mean,
                          const float* __restrict__ rstd, const float* __restrict__ g,
                          const float* __restrict__ b, short* __restrict__ tok){
  __shared__ float tile[64][65];
  const int w = blockIdx.x, ct = blockIdx.y * 64;
  const int wh = w / 12, ww = w - wh * 12;
  const int t = threadIdx.x;
  for (int e = t; e < 4096; e += 256){        // lanes over pixels
    const int cl = e >> 6, pix = e & 63;
    int pr = wh * 8 + (pix >> 3) + 4; if (pr >= 96) pr -= 96;
    int pc = ww * 8 + (pix & 7) + 4;  if (pc >= 96) pc -= 96;
    tile[pix][cl] = x[(long)(ct + cl) * 9216 + pr * 96 + pc];
  }
  __syncthreads();
  for (int e = t; e < 4096; e += 256){        // lanes over channels
    const int pix = e >> 6, cl = e & 63;
    int pr = wh * 8 + (pix >> 3) + 4; if (pr >= 96) pr -= 96;
    int pc = ww * 8 + (pix & 7) + 4;  if (pc >= 96) pc -= 96;
    const int p = pr * 96 + pc;
    float v = (tile[pix][cl] - mean[p]) * rstd[p] * g[ct + cl] + b[ct + cl];
    tok[(long)(w * 64 + pix) * 768 + ct + cl] = f2bf(v);
  }
}

// ---------------- windowed residual merge: x1 = x + scatter(ptok) ----------------
__global__ void k_merge_win(const float* __restrict__ x, const short* __restrict__ ptok,
                            float* __restrict__ x1){
  __shared__ float tile[64][65];
  const int w = blockIdx.x, ct = blockIdx.y * 64;
  const int wh = w / 12, ww = w - wh * 12;
  const int t = threadIdx.x;
  for (int e = t; e < 4096; e += 256){        // lanes over channels (coalesced bf16 read)
    const int pix = e >> 6, cl = e & 63;
    tile[pix][cl] = bf2f(ptok[(long)(w * 64 + pix) * 768 + ct + cl]);
  }
  __syncthreads();
  for (int e = t; e < 4096; e += 256){        // lanes over pixels
    const int cl = e >> 6, pix = e & 63;
    int pr = wh * 8 + (pix >> 3) + 4; if (pr >= 96) pr -= 96;
    int pc = ww * 8 + (pix & 7) + 4;  if (pc >= 96) pc -= 96;
    const long gi = (long)(ct + cl) * 9216 + pr * 96 + pc;
    x1[gi] = x[gi] + tile[pix][cl];
  }
}

// ---------------- LN2 (raster order) -> bf16 tokens ----------------
__global__ void k_ln2_raster(const float* __restrict__ x1, const float* __restrict__ mean,
                             const float* __restrict__ rstd, const float* __restrict__ g,
                             const float* __restrict__ b, short* __restrict__ tok){
  __shared__ float tile[96][65];
  const int hrow = blockIdx.x, ct = blockIdx.y * 64;
  const int t = threadIdx.x;
  for (int e = t; e < 6144; e += 256){
    const int cl = e / 96, p = e - cl * 96;
    tile[p][cl] = x1[(long)(ct + cl) * 9216 + hrow * 96 + p];
  }
  __syncthreads();
  for (int e = t; e < 6144; e += 256){
    const int p = e >> 6, cl = e & 63;
    const int gp = hrow * 96 + p;
    float v = (tile[p][cl] - mean[gp]) * rstd[gp] * g[ct + cl] + b[ct + cl];
    tok[(long)gp * 768 + ct + cl] = f2bf(v);
  }
}

// ---------------- final merge (raster): out = x1 + mtok ----------------
__global__ void k_merge_raster(const float* __restrict__ x1, const short* __restrict__ mtok,
                               float* __restrict__ out){
  __shared__ float tile[96][65];
  const int hrow = blockIdx.x, ct = blockIdx.y * 64;
  const int t = threadIdx.x;
  for (int e = t; e < 6144; e += 256){
    const int p = e >> 6, cl = e & 63;
    tile[p][cl] = bf2f(mtok[(long)(hrow * 96 + p) * 768 + ct + cl]);
  }
  __syncthreads();
  for (int e = t; e < 6144; e += 256){
    const int cl = e / 96, p = e - cl * 96;
    const long gi = (long)(ct + cl) * 9216 + hrow * 96 + p;
    out[gi] = x1[gi] + tile[p][cl];
  }
}

// ---------------- MFMA GEMM 128x128, BK=32, 4 waves ----------------
// XCD-bijective block swizzle (m204) for L2 locality + 2-phase pipeline
// (stage next -> ds_read cur -> lgkmcnt(0) -> MFMA -> vmcnt(0) -> raw barrier):
// no vmcnt(0)-before-compute drain, so the stage latency hides under read+MFMA.
__global__ __launch_bounds__(256) void k_gemm_bt(
    const short* __restrict__ A, const short* __restrict__ B,
    const float* __restrict__ bias, short* __restrict__ C,
    int N, int K, int NBN, int do_gelu)
{
  __shared__ short Al[2][4096];
  __shared__ short Bl[2][4096];
  const int tid = threadIdx.x;
  const int wave = tid >> 6, lane = tid & 63;
  const int l15 = lane & 15, lg = lane >> 4;

  // XCD swizzle: hw block i runs on XCD i%8 (round-robin dispatch);
  // give each XCD a contiguous logical chunk (bijective for any nb).
  const int nb = gridDim.x;
  const int q = nb >> 3, r = nb & 7;
  const int xcd = blockIdx.x & 7, loc = blockIdx.x >> 3;
  const int swz = (xcd < r ? xcd * (q + 1) : r * (q + 1) + (xcd - r) * q) + loc;
  const int bn = swz % NBN, bm = swz / NBN;

  const long Abase = (long)bm * 128 * K;
  const long Bbase = (long)bn * 128 * K;
  const int srow = tid >> 2;           // staging row
  const int scol = (tid & 3) << 3;     // staging col (shorts)
  const int wr = (wave >> 1) * 64, wc = (wave & 1) * 64;

  f32x4 acc[4][4] = {};

  auto stage = [&](int buf, int k0){
    const short* gA = A + Abase + (long)srow * K + k0 + scol;
    const short* gB = B + Bbase + (long)srow * K + k0 + scol;
    short* lA = &Al[buf][wave * 512];
    short* lB = &Bl[buf][wave * 512];
    gl2lds16(gA, lA);
    gl2lds16(gA + (long)64 * K, lA + 2048);
    gl2lds16(gB, lB);
    gl2lds16(gB + (long)64 * K, lB + 2048);
  };

  const int NKT = K >> 5;
  stage(0, 0);
  asm volatile("s_waitcnt vmcnt(0)" ::: "memory");
  __builtin_amdgcn_s_barrier();

  int buf = 0;
  for (int kt = 0; kt < NKT; ++kt){
    if (kt + 1 < NKT) stage(buf ^ 1, (kt + 1) << 5);   // in flight across this iter
    bf16x8 af[4], bfv[4];
    #pragma unroll
    for (int m = 0; m < 4; ++m)
      af[m] = *(const bf16x8*)&Al[buf][(wr + m * 16 + l15) * 32 + lg * 8];
    #pragma unroll
    for (int n2 = 0; n2 < 4; ++n2)
      bfv[n2] = *(const bf16x8*)&Bl[buf][(wc + n2 * 16 + l15) * 32 + lg * 8];
    asm volatile("s_waitcnt lgkmcnt(0)" ::: "memory");   // reads drained (pre-barrier)
    __builtin_amdgcn_sched_barrier(0);
    #pragma unroll
    for (int m = 0; m < 4; ++m)
      #pragma unroll
      for (int n2 = 0; n2 < 4; ++n2)
        acc[m][n2] = __builtin_amdgcn_mfma_f32_16x16x32_bf16(af[m], bfv[n2], acc[m][n2], 0, 0, 0);
    asm volatile("s_waitcnt vmcnt(0)" ::: "memory");     // next-tile stage landed
    __builtin_amdgcn_s_barrier();
    buf ^= 1;
  }

  const long row0 = (long)bm * 128 + wr + lg * 4;
  const int col0 = bn * 128 + wc + l15;
  #pragma unroll
  for (int m = 0; m < 4; ++m){
    #pragma unroll
    for (int n2 = 0; n2 < 4; ++n2){
      const int col = col0 + n2 * 16;
      const float bb = bias[col];
      #pragma unroll
      for (int r2 = 0; r2 < 4; ++r2){
        float v = acc[m][n2][r2] + bb;
        if (do_gelu) v = gelu_tanh(v);
        C[(row0 + m * 16 + r2) * (long)N + col] = f2bf(v);
      }
    }
  }
}

// ---------------- MFMA attention: one wave per (window, head) ----------------
#define PSTR 72
__global__ __launch_bounds__(256) void k_attn_mfma(
    const short* __restrict__ qkv, const float* __restrict__ biasp,
    short* __restrict__ out)
{
  __shared__ short Pl[4][64 * PSTR];
  const int tid = threadIdx.x, wv = tid >> 6, lane = tid & 63;
  const int l15 = lane & 15, lg = lane >> 4;
  const int task = blockIdx.x * 4 + wv;          // 0..3455
  const int w = task / 24, h = task - w * 24;
  const int wh = w / 12, ww = w - wh * 12;
  const long base = (long)w * 64 * 2304;
  const float scale = 0.17677669529663687f;      // 1/sqrt(32)

  bf16x8 qf[4], kf[4];
  #pragma unroll
  for (int mi = 0; mi < 4; ++mi)
    qf[mi] = *(const bf16x8*)(qkv + base + (long)(mi * 16 + l15) * 2304 + h * 32 + lg * 8);
  #pragma unroll
  for (int ni = 0; ni < 4; ++ni)
    kf[ni] = *(const bf16x8*)(qkv + base + (long)(ni * 16 + l15) * 2304 + 768 + h * 32 + lg * 8);

  f32x4 acc[4][4] = {};
  #pragma unroll
  for (int mi = 0; mi < 4; ++mi)
    #pragma unroll
    for (int ni = 0; ni < 4; ++ni)
      acc[mi][ni] = __builtin_amdgcn_mfma_f32_16x16x32_bf16(qf[mi], kf[ni], acc[mi][ni], 0, 0, 0);

  const float* bh = biasp + h * 4096;
  #pragma unroll
  for (int mi = 0; mi < 4; ++mi){
    #pragma unroll
    for (int r = 0; r < 4; ++r){
      const int m = mi * 16 + lg * 4 + r;
      const int i1 = m >> 3, j1 = m & 7;
      const int labm = ((wh == 11) ? ((i1 >= 4) ? 2 : 1) : 0) * 3
                     + ((ww == 11) ? ((j1 >= 4) ? 2 : 1) : 0);
      #pragma unroll
      for (int ni = 0; ni < 4; ++ni){
        const int n = ni * 16 + l15;
        const int i2 = n >> 3, j2 = n & 7;
        const int labn = ((wh == 11) ? ((i2 >= 4) ? 2 : 1) : 0) * 3
                       + ((ww == 11) ? ((j2 >= 4) ? 2 : 1) : 0);
        float s = acc[mi][ni][r] * scale + bh[m * 64 + n];
        if (labm != labn) s -= 100.f;
        acc[mi][ni][r] = s;
      }
    }
  }

  float inv[4][4];
  #pragma unroll
  for (int mi = 0; mi < 4; ++mi){
    #pragma unroll
    for (int r = 0; r < 4; ++r){
      float mx = fmaxf(fmaxf(acc[mi][0][r], acc[mi][1][r]),
                       fmaxf(acc[mi][2][r], acc[mi][3][r]));
      #pragma unroll
      for (int off = 1; off < 16; off <<= 1) mx = fmaxf(mx, __shfl_xor(mx, off));
      float sum = 0.f;
      #pragma unroll
      for (int ni = 0; ni < 4; ++ni){
        float e = __expf(acc[mi][ni][r] - mx);
        acc[mi][ni][r] = e;
        sum += e;
      }
      #pragma unroll
      for (int off = 1; off < 16; off <<= 1) sum += __shfl_xor(sum, off);
      inv[mi][r] = 1.f / sum;
    }
  }

  short* pw = &Pl[wv][0];
  #pragma unroll
  for (int mi = 0; mi < 4; ++mi)
    #pragma unroll
    for (int ni = 0; ni < 4; ++ni)
      #pragma unroll
      for (int r = 0; r < 4; ++r)
        pw[(mi * 16 + lg * 4 + r) * PSTR + ni * 16 + l15] = f2bf(acc[mi][ni][r]);
  __syncthreads();

  f32x4 acc2[4][2] = {};
  #pragma unroll
  for (int kk = 0; kk < 2; ++kk){
    bf16x8 pa[4], vb[2];
    #pragma unroll
    for (int mi = 0; mi < 4; ++mi)
      pa[mi] = *(const bf16x8*)&pw[(mi * 16 + l15) * PSTR + kk * 32 + lg * 8];
    #pragma unroll
    for (int dj = 0; dj < 2; ++dj){
      bf16x8 t;
      #pragma unroll
      for (int e = 0; e < 8; ++e)
        t[e] = qkv[base + (long)(kk * 32 + lg * 8 + e) * 2304 + 1536 + h * 32 + dj * 16 + l15];
      vb[dj] = t;
    }
    #pragma unroll
    for (int mi = 0; mi < 4; ++mi)
      #pragma unroll
      for (int dj = 0; dj < 2; ++dj)
        acc2[mi][dj] = __builtin_amdgcn_mfma_f32_16x16x32_bf16(pa[mi], vb[dj], acc2[mi][dj], 0, 0, 0);
  }

  #pragma unroll
  for (int mi = 0; mi < 4; ++mi){
    #pragma unroll
    for (int r = 0; r < 4; ++r){
      const int m = mi * 16 + lg * 4 + r;
      const long ob = (long)(w * 64 + m) * 768 + h * 32;
      #pragma unroll
      for (int dj = 0; dj < 2; ++dj)
        out[ob + dj * 16 + l15] = f2bf(acc2[mi][dj][r] * inv[mi][r]);
    }
  }
}

// ---------------- launch ----------------
extern "C" void kernel_launch(void* const* d_in, const int* in_sizes, int n_in,
                              void* d_out, int out_size, void* d_ws, size_t ws_size,
                              hipStream_t stream)
{
  const float* x      = (const float*)d_in[0];
  const float* n1w    = (const float*)d_in[1];
  const float* n1b    = (const float*)d_in[2];
  const float* qkv_w  = (const float*)d_in[3];
  const float* qkv_b  = (const float*)d_in[4];
  const float* proj_w = (const float*)d_in[5];
  const float* proj_b = (const float*)d_in[6];
  const float* btab   = (const float*)d_in[7];
  const float* n2w    = (const float*)d_in[8];
  const float* n2b    = (const float*)d_in[9];
  const float* fc1_w  = (const float*)d_in[10];
  const float* fc1_b  = (const float*)d_in[11];
  const float* fc2_w  = (const float*)d_in[12];
  const float* fc2_b  = (const float*)d_in[13];
  float* out = (float*)d_out;
  char* ws = (char*)d_ws;

  short* WQ   = (short*)(ws + 0);           // 2304x768 bf16
  short* WP   = (short*)(ws + 3538944);     // 768x768
  short* W1   = (short*)(ws + 4718592);     // 3072x768
  short* W2   = (short*)(ws + 9437184);     // 768x3072
  float* SUMS = (float*)(ws + 14155776);    // 9216
  float* SUMSQ= (float*)(ws + 14192640);    // 9216
  float* MEAN = (float*)(ws + 14229504);
  float* RSTD = (float*)(ws + 14266368);
  float* BIASP= (float*)(ws + 14303232);    // 24*64*64 f32
  short* TOK  = (short*)(ws + 14696448);    // 9216x768 bf16
  short* BIG  = (short*)(ws + 28852224);    // 9216x2304 (qkv) / 9216x3072 (hid)
  short* ATT  = (short*)(ws + 85475328);    // 9216x768
  short* PRJ  = (short*)(ws + 99631104);    // 9216x768
  float* X1   = (float*)(ws + 113786880);   // 768x9216 f32

  k_f2b<<<(2304 * 768 + 255) / 256, 256, 0, stream>>>(qkv_w, WQ, 2304 * 768);
  k_f2b<<<(768 * 768 + 255) / 256, 256, 0, stream>>>(proj_w, WP, 768 * 768);
  k_f2b<<<(3072 * 768 + 255) / 256, 256, 0, stream>>>(fc1_w, W1, 3072 * 768);
  k_f2b<<<(768 * 3072 + 255) / 256, 256, 0, stream>>>(fc2_w, W2, 768 * 3072);
  k_bias_pre<<<(24 * 4096) / 256, 256, 0, stream>>>(btab, BIASP);

  hipMemsetAsync(SUMS, 0, 2 * 9216 * 4, stream);
  k_ln_stats<<<dim3(36, 12), 256, 0, stream>>>(x, SUMS, SUMSQ);
  k_ln_fin<<<36, 256, 0, stream>>>(SUMS, SUMSQ, MEAN, RSTD);
  k_ln1_win<<<dim3(144, 12), 256, 0, stream>>>(x, MEAN, RSTD, n1w, n1b, TOK);

  k_gemm_bt<<<18 * 72, 256, 0, stream>>>(TOK, WQ, qkv_b, BIG, 2304, 768, 18, 0);
  k_attn_mfma<<<864, 256, 0, stream>>>(BIG, BIASP, ATT);
  k_gemm_bt<<<6 * 72, 256, 0, stream>>>(ATT, WP, proj_b, PRJ, 768, 768, 6, 0);
  k_merge_win<<<dim3(144, 12), 256, 0, stream>>>(x, PRJ, X1);

  hipMemsetAsync(SUMS, 0, 2 * 9216 * 4, stream);
  k_ln_stats<<<dim3(36, 12), 256, 0, stream>>>(X1, SUMS, SUMSQ);
  k_ln_fin<<<36, 256, 0, stream>>>(SUMS, SUMSQ, MEAN, RSTD);
  k_ln2_raster<<<dim3(96, 12), 256, 0, stream>>>(X1, MEAN, RSTD, n2w, n2b, TOK);

  k_gemm_bt<<<24 * 72, 256, 0, stream>>>(TOK, W1, fc1_b, BIG, 3072, 768, 24, 1);
  k_gemm_bt<<<6 * 72, 256, 0, stream>>>(BIG, W2, fc2_b, ATT, 768, 3072, 6, 0);
  k_merge_raster<<<dim3(96, 12), 256, 0, stream>>>(X1, ATT, out);
}